// Round 7
// baseline (457.922 us; speedup 1.0000x reference)
//
#include <hip/hip_runtime.h>
#include <hip/hip_bf16.h>

#define F 2048
#define MBATCH 16384
#define BM 256
#define BN 256
#define BK 32
#define PL (BM * BK)          // shorts per plane (8192 = 16 KB)
#define THREADS 512

typedef short bf16x8 __attribute__((ext_vector_type(8)));  // MFMA A/B frag (4 VGPR)
typedef float f32x4 __attribute__((ext_vector_type(4)));   // MFMA C/D frag

static __device__ __forceinline__ unsigned short bfb(float v) {
    return __builtin_bit_cast(unsigned short, __float2bfloat16(v));
}
static __device__ __forceinline__ float bff(unsigned short u) {
    return __bfloat162float(__builtin_bit_cast(__hip_bfloat16, u));
}
// pack top-16 bits of two f32 -> [hi16(b) : hi16(a)]  (1 v_perm)
static __device__ __forceinline__ unsigned pack_hi16(float a, float b) {
    return __builtin_amdgcn_perm(__builtin_bit_cast(unsigned, b),
                                 __builtin_bit_cast(unsigned, a), 0x07060302u);
}
static __device__ __forceinline__ float trunc_hi(float v) {
    return __builtin_bit_cast(float, __builtin_bit_cast(unsigned, v) & 0xffff0000u);
}
static __device__ __forceinline__ unsigned cvtpk_bf16(float a, float b) {
    unsigned r;
    asm("v_cvt_pk_bf16_f32 %0, %1, %2" : "=v"(r) : "v"(a), "v"(b));
    return r;   // low16 = bf16(a), high16 = bf16(b)
}

// ---------------- build transposed upper-tri B planes (hi/lo bf16) ----------------
__global__ __launch_bounds__(256) void build_bt(const float* __restrict__ bw,
                                                unsigned short* __restrict__ bt_hi,
                                                unsigned short* __restrict__ bt_lo) {
    __shared__ unsigned short tH[64][72], tL[64][72];
    const int bx = blockIdx.x & 31;   // j1 tile
    const int by = blockIdx.x >> 5;   // j2 tile
    const int r  = threadIdx.x >> 2;          // 0..63
    const int cg = (threadIdx.x & 3) * 16;    // col-group start
    const bool up = (by >= bx);
    if (up) {
        int j1 = bx * 64 + r;
        long base = (long)j1 * F - (((long)j1 * (j1 + 1)) >> 1) - j1 - 1;
#pragma unroll
        for (int c = 0; c < 16; ++c) {
            int j2 = by * 64 + cg + c;
            float v = (j2 > j1) ? bw[base + j2] : 0.f;
            unsigned short h = bfb(v);
            tH[r][cg + c] = h;
            tL[r][cg + c] = bfb(v - bff(h));
        }
    }
    __syncthreads();
    size_t obase = (size_t)(by * 64 + r) * F + bx * 64 + cg;   // out row j2, cols j1
    uint4 H0 = {0,0,0,0}, H1 = {0,0,0,0}, L0 = {0,0,0,0}, L1 = {0,0,0,0};
    if (up) {
        unsigned oh[16], ol[16];
#pragma unroll
        for (int c = 0; c < 16; ++c) { oh[c] = tH[cg + c][r]; ol[c] = tL[cg + c][r]; }
        H0.x = oh[0] | (oh[1] << 16);  H0.y = oh[2] | (oh[3] << 16);
        H0.z = oh[4] | (oh[5] << 16);  H0.w = oh[6] | (oh[7] << 16);
        H1.x = oh[8] | (oh[9] << 16);  H1.y = oh[10] | (oh[11] << 16);
        H1.z = oh[12] | (oh[13] << 16); H1.w = oh[14] | (oh[15] << 16);
        L0.x = ol[0] | (ol[1] << 16);  L0.y = ol[2] | (ol[3] << 16);
        L0.z = ol[4] | (ol[5] << 16);  L0.w = ol[6] | (ol[7] << 16);
        L1.x = ol[8] | (ol[9] << 16);  L1.y = ol[10] | (ol[11] << 16);
        L1.z = ol[12] | (ol[13] << 16); L1.w = ol[14] | (ol[15] << 16);
    }
    *(uint4*)(bt_hi + obase)     = H0;
    *(uint4*)(bt_hi + obase + 8) = H1;
    *(uint4*)(bt_lo + obase)     = L0;
    *(uint4*)(bt_lo + obase + 8) = L1;
}

// ---------------- main GEMM: y = x * B (upper-tri), fused epilogue ----------------
// 256x256 tile, BK=32, 8 waves (2x4), double-buffered 128 KiB LDS, paired-row
// swizzle (slot s of row-pair rp holds h = s ^ (rp&7); h>>2 = row parity, h&3 = kchunk).
// 8-phase-style schedule: 4 quadrant phases per kt, each {ds_read frags || stage,
// s_barrier, lgkmcnt(0), setprio(1), 24 MFMA, setprio(0), s_barrier}.
__global__ __launch_bounds__(THREADS, 2) void poly2_gemm(
        const float* __restrict__ x,
        const unsigned short* __restrict__ bt_hi,
        const unsigned short* __restrict__ bt_lo,
        const float* __restrict__ w,
        float* __restrict__ cross_acc) {
    extern __shared__ unsigned short smem[];   // [2 buf][4 planes][PL]

    const int tid  = threadIdx.x;
    const int lane = tid & 63;
    const int wid  = tid >> 6;         // 0..7
    const int wm   = wid >> 2;         // 0..1 : 128-row band
    const int wn   = wid & 3;          // 0..3 : 64-col band
    const int lr   = lane & 15;
    const int lg   = lane >> 4;

    // pair heavy nt with light nt so each CU's resident blocks sum to equal work
    const int g  = blockIdx.x >> 6;
    const int nt = (g < 4) ? (7 - g) : (g - 4);
    const int mt = blockIdx.x & 63;
    const int m0 = mt * BM;
    const int n0 = nt * BN;
    const int ktiles = 8 * (nt + 1);   // triangular skip: kt*32 < (nt+1)*256

    f32x4 acc[8][4] = {};

    // ---- staging helpers (quarter-granularity) ----
    auto stageB_it = [&](int buf, int k0, int it) {
        unsigned short* Bh = smem + buf * 4 * PL + 2 * PL;
        unsigned short* Bl = Bh + PL;
        int q  = it * THREADS + tid;
        int rp = q >> 3, s = q & 7;
        int h  = s ^ (rp & 7);
        int col  = n0 + 2 * rp + (h >> 2);
        int koff = k0 + (h & 3) * 8;
        const unsigned short* ghi = bt_hi + (size_t)col * F + koff;
        const unsigned short* glo = bt_lo + (size_t)col * F + koff;
        unsigned short* dh = Bh + (q & ~63) * 8;   // wave-uniform base + lane*16B
        unsigned short* dl = Bl + (q & ~63) * 8;
        __builtin_amdgcn_global_load_lds(
            (const __attribute__((address_space(1))) unsigned int*)ghi,
            (__attribute__((address_space(3))) unsigned int*)dh, 16, 0, 0);
        __builtin_amdgcn_global_load_lds(
            (const __attribute__((address_space(1))) unsigned int*)glo,
            (__attribute__((address_space(3))) unsigned int*)dl, 16, 0, 0);
    };
    auto loadA_it = [&](int k0, int it, float4& a, float4& b) {
        int q  = it * THREADS + tid;
        int rp = q >> 3, s = q & 7;
        int h  = s ^ (rp & 7);
        const float* src = x + (size_t)(m0 + 2 * rp + (h >> 2)) * F + k0 + (h & 3) * 8;
        a = ((const float4*)src)[0];
        b = ((const float4*)src)[1];
    };
    auto writeA_it = [&](int buf, int it, float4 a, float4 b) {
        unsigned short* Ah = smem + buf * 4 * PL;
        unsigned short* Al = Ah + PL;
        int q = it * THREADS + tid;
        uint4 H, L;
        H.x = pack_hi16(a.x, a.y); H.y = pack_hi16(a.z, a.w);
        H.z = pack_hi16(b.x, b.y); H.w = pack_hi16(b.z, b.w);
        L.x = cvtpk_bf16(a.x - trunc_hi(a.x), a.y - trunc_hi(a.y));
        L.y = cvtpk_bf16(a.z - trunc_hi(a.z), a.w - trunc_hi(a.w));
        L.z = cvtpk_bf16(b.x - trunc_hi(b.x), b.y - trunc_hi(b.y));
        L.w = cvtpk_bf16(b.z - trunc_hi(b.z), b.w - trunc_hi(b.w));
        *(uint4*)&Ah[q * 8] = H;   // linear dest: conflict-free
        *(uint4*)&Al[q * 8] = L;
    };
    // ---- fragment readers ----
    auto readA = [&](const unsigned short* Ah, const unsigned short* Al,
                     int mh, bf16x8* ah, bf16x8* al) {
#pragma unroll
        for (int m2 = 0; m2 < 4; ++m2) {
            int r  = wm * 128 + mh * 64 + m2 * 16 + lr;
            int rp = r >> 1;
            int off = rp * 64 + ((((r & 1) << 2) + lg) ^ (rp & 7)) * 8;
            ah[m2] = *(const bf16x8*)&Ah[off];
            al[m2] = *(const bf16x8*)&Al[off];
        }
    };
    auto readB = [&](const unsigned short* Bh, const unsigned short* Bl,
                     int nh, bf16x8* bh, bf16x8* bl) {
#pragma unroll
        for (int j = 0; j < 2; ++j) {
            int c  = wn * 64 + (nh * 2 + j) * 16 + lr;
            int rp = c >> 1;
            int off = rp * 64 + ((((c & 1) << 2) + lg) ^ (rp & 7)) * 8;
            bh[j] = *(const bf16x8*)&Bh[off];
            bl[j] = *(const bf16x8*)&Bl[off];
        }
    };
    auto quad = [&](int mh, int nh, const bf16x8* ah, const bf16x8* al,
                    const bf16x8* bh, const bf16x8* bl) {
#pragma unroll
        for (int m2 = 0; m2 < 4; ++m2)
#pragma unroll
            for (int j = 0; j < 2; ++j) {
                int n = nh * 2 + j;
                f32x4 c0 = acc[mh * 4 + m2][n];
                c0 = __builtin_amdgcn_mfma_f32_16x16x32_bf16(ah[m2], bh[j], c0, 0, 0, 0);
                c0 = __builtin_amdgcn_mfma_f32_16x16x32_bf16(ah[m2], bl[j], c0, 0, 0, 0);
                c0 = __builtin_amdgcn_mfma_f32_16x16x32_bf16(al[m2], bh[j], c0, 0, 0, 0);
                acc[mh * 4 + m2][n] = c0;
            }
    };

#define PHASE_GO()  do { __builtin_amdgcn_s_barrier();                         \
                         asm volatile("s_waitcnt lgkmcnt(0)" ::: "memory");    \
                         __builtin_amdgcn_sched_barrier(0);                    \
                         __builtin_amdgcn_s_setprio(1); } while (0)
#define PHASE_END() do { __builtin_amdgcn_s_setprio(0);                        \
                         __builtin_amdgcn_s_barrier(); } while (0)

    // ---- prologue: fill buf 0 ----
    {
        float4 a0, b0, a1, b1;
        stageB_it(0, 0, 0); stageB_it(0, 0, 1);
        loadA_it(0, 0, a0, b0); loadA_it(0, 1, a1, b1);
        writeA_it(0, 0, a0, b0); writeA_it(0, 1, a1, b1);
    }
    __syncthreads();

    int cur = 0;
    for (int kt = 0; kt < ktiles; ++kt) {
        const bool more = (kt + 1) < ktiles;
        const int k1 = (kt + 1) * BK;
        const unsigned short* Ah = smem + cur * 4 * PL;
        const unsigned short* Al = Ah + PL;
        const unsigned short* Bh = Al + PL;
        const unsigned short* Bl = Bh + PL;
        bf16x8 ah[4], al[4], bh[2], bl[2];
        float4 r0a, r0b, r1a, r1b;

        // phase 0: read A(mh0)+B(nh0); issue stage quarter 0
        readA(Ah, Al, 0, ah, al);
        readB(Bh, Bl, 0, bh, bl);
        if (more) { stageB_it(cur ^ 1, k1, 0); loadA_it(k1, 0, r0a, r0b); }
        PHASE_GO();  quad(0, 0, ah, al, bh, bl);  PHASE_END();

        // phase 1: read B(nh1); issue stage quarter 1
        readB(Bh, Bl, 1, bh, bl);
        if (more) { stageB_it(cur ^ 1, k1, 1); loadA_it(k1, 1, r1a, r1b); }
        PHASE_GO();  quad(0, 1, ah, al, bh, bl);  PHASE_END();

        // phase 2: read A(mh1); convert+write half 0 (B nh1 reused in regs)
        readA(Ah, Al, 1, ah, al);
        if (more) writeA_it(cur ^ 1, 0, r0a, r0b);
        PHASE_GO();  quad(1, 1, ah, al, bh, bl);  PHASE_END();

        // phase 3: read B(nh0); convert+write half 1
        readB(Bh, Bl, 0, bh, bl);
        if (more) writeA_it(cur ^ 1, 1, r1a, r1b);
        PHASE_GO();  quad(1, 0, ah, al, bh, bl);
        __builtin_amdgcn_s_setprio(0);
        __syncthreads();                         // buffer flip: full drain (correctness)
        cur ^= 1;
    }
#undef PHASE_GO
#undef PHASE_END

    // ---- epilogue: (y + w) dot x per row, 16-lane shuffle reduce, atomic accumulate ----
#pragma unroll
    for (int m = 0; m < 8; ++m) {
#pragma unroll
        for (int r = 0; r < 4; ++r) {
            int grow = m0 + wm * 128 + m * 16 + lg * 4 + r;
            float sum = 0.f;
#pragma unroll
            for (int n = 0; n < 4; ++n) {
                int gcol = n0 + wn * 64 + n * 16 + lr;
                float yv = acc[m][n][r] + w[gcol];
                sum += yv * x[(size_t)grow * F + gcol];
            }
            sum += __shfl_xor(sum, 1);
            sum += __shfl_xor(sum, 2);
            sum += __shfl_xor(sum, 4);
            sum += __shfl_xor(sum, 8);
            if (lr == 0) atomicAdd(&cross_acc[grow], sum);
        }
    }
}

// ---------------- final sigmoid ----------------
__global__ __launch_bounds__(256) void finish_sigmoid(const float* __restrict__ cross,
                                                      const float* __restrict__ w0,
                                                      float* __restrict__ out) {
    int b = blockIdx.x * 256 + threadIdx.x;
    float z = cross[b] + w0[0];
    out[b] = 1.f / (1.f + expf(-z));
}

extern "C" void kernel_launch(void* const* d_in, const int* in_sizes, int n_in,
                              void* d_out, int out_size, void* d_ws, size_t ws_size,
                              hipStream_t stream) {
    const float* x  = (const float*)d_in[0];
    const float* w0 = (const float*)d_in[1];
    const float* w  = (const float*)d_in[2];
    const float* bw = (const float*)d_in[3];
    float* out = (float*)d_out;

    // ws layout: [cross_acc: MBATCH f32][bt_hi: F*F bf16][bt_lo: F*F bf16]  (~16.9 MB)
    float* cross = (float*)d_ws;
    unsigned short* bt_hi = (unsigned short*)((char*)d_ws + (size_t)MBATCH * sizeof(float));
    unsigned short* bt_lo = bt_hi + (size_t)F * F;

    // allow 128 KiB dynamic LDS (idempotent; safe under graph capture)
    hipFuncSetAttribute((const void*)poly2_gemm,
                        hipFuncAttributeMaxDynamicSharedMemorySize, 131072);

    hipMemsetAsync(cross, 0, (size_t)MBATCH * sizeof(float), stream);
    build_bt<<<(F / 64) * (F / 64), 256, 0, stream>>>(bw, bt_hi, bt_lo);
    poly2_gemm<<<(MBATCH / BM) * (F / BN), THREADS, 131072, stream>>>(x, bt_hi, bt_lo, w, cross);
    finish_sigmoid<<<MBATCH / 256, 256, 0, stream>>>(cross, w0, out);
}